// Round 7
// baseline (194.937 us; speedup 1.0000x reference)
//
#include <hip/hip_runtime.h>

#define NPTS   524288
#define TBLM   ((1u << 19) - 1u)
#define THR    256
#define CHUNK  64            // points per chunk (4 waves x 16)
#define CHUNKS 8
#define GRID   (NPTS / (CHUNK * CHUNKS))   // 1024

typedef _Float16 half8  __attribute__((ext_vector_type(8)));
typedef _Float16 half4v __attribute__((ext_vector_type(4)));
typedef _Float16 half2v __attribute__((ext_vector_type(2)));
typedef float    f32x4  __attribute__((ext_vector_type(4)));

// d_ws layout (halves): W1 frags [m4][kc2][lane64][j8] @0 (4096)
//                       W2 frags [m5][kc2][lane][j]   @4096 (5120)
//                       W3 frags [m4][kc3][lane][j]   @9216 (6144)
//                       W4 frags [kc2][lane][j]       @15360 (1024)
// floats @byte 32768: b1[64], b2[80], b3[64], b4[16]  (224 floats)

__global__ __launch_bounds__(256)
void prep(const float* __restrict__ dw1, const float* __restrict__ db1,
          const float* __restrict__ dw2, const float* __restrict__ db2,
          const float* __restrict__ rw1, const float* __restrict__ rb1,
          const float* __restrict__ rw2, const float* __restrict__ rb2,
          void* __restrict__ ws)
{
    const int t = blockIdx.x * 256 + threadIdx.x;
    if (t < 16384) {
        float w = 0.0f;
        if (t < 4096) {                       // W1: k' permuted (39 dead, grid at 40..47)
            const int u = t, mkc = u >> 9, m = mkc >> 1, kc = mkc & 1;
            const int lane = (u >> 3) & 63, j = u & 7;
            const int row = 16 * m + (lane & 15);
            const int kp  = kc * 32 + (lane >> 4) * 8 + j;
            if (kp < 39)      w = dw1[kp * 64 + row];
            else if (kp == 39) w = 0.0f;
            else if (kp < 48) w = dw1[(kp - 1) * 64 + row];
        } else if (t < 9216) {                // W2
            const int u = t - 4096, mkc = u >> 9, m = mkc >> 1, kc = mkc & 1;
            const int lane = (u >> 3) & 63, j = u & 7;
            const int row = 16 * m + (lane & 15);
            const int k   = kc * 32 + (lane >> 4) * 8 + j;
            if (row < 65) w = dw2[k * 65 + row];
        } else if (t < 15360) {               // W3: col0 dead, feat@1..64, sh3@65..73
            const int u = t - 9216, mkc = u >> 9, m = mkc / 3, kc = mkc - 3 * m;
            const int lane = (u >> 3) & 63, j = u & 7;
            const int row = 16 * m + (lane & 15);
            const int kp  = kc * 32 + (lane >> 4) * 8 + j;
            if (kp >= 1 && kp <= 73) w = rw1[(kp - 1) * 64 + row];
        } else {                              // W4
            const int u = t - 15360, kc = u >> 9;
            const int lane = (u >> 3) & 63, j = u & 7;
            const int row = lane & 15;
            const int k   = kc * 32 + (lane >> 4) * 8 + j;
            if (row < 3) w = rw2[k * 3 + row];
        }
        ((_Float16*)ws)[t] = (_Float16)w;
    } else if (t < 16384 + 224) {
        const int u = t - 16384;
        float b = 0.0f;
        if (u < 64)        b = db1[u];
        else if (u < 144)  { const int r = u - 64;  if (r < 65) b = db2[r]; }
        else if (u < 208)  b = rb1[u - 144];
        else               { const int r = u - 208; if (r < 3)  b = rb2[r]; }
        ((float*)((char*)ws + 32768))[u] = b;
    }
}

__device__ __forceinline__ float sstep(float t) { return t * t * (3.0f - 2.0f * t); }

// Per-lane pipelined gather state (all members statically addressed -> registers).
struct GS {
    float  x0, x1, x2, v0, v1, v2;
    float  ax, ay, az;
    float2 t0, t1, t2, t3, t4, t5, t6, t7;
};

__device__ __forceinline__ void gather_issue(int gi, int role,
    const float* __restrict__ x, const float* __restrict__ v,
    const float* __restrict__ table, GS& s)
{
    s.x0 = x[3 * gi + 0]; s.x1 = x[3 * gi + 1]; s.x2 = x[3 * gi + 2];
    if (role == 1) { s.v0 = v[3 * gi + 0]; s.v1 = v[3 * gi + 1]; s.v2 = v[3 * gi + 2]; }
    const float rf = (role == 0) ? 33.f : (role == 1) ? 43.f : (role == 2) ? 56.f : 74.f;
    const float u0 = (s.x0 + 1.f) * 0.5f, u1 = (s.x1 + 1.f) * 0.5f, u2 = (s.x2 + 1.f) * 0.5f;
    const float px = u0 * rf, py = u1 * rf, pz = u2 * rf;
    const float fx = floorf(px), fy = floorf(py), fz = floorf(pz);
    s.ax = sstep(px - fx); s.ay = sstep(py - fy); s.az = sstep(pz - fz);
    const unsigned cx = (unsigned)fx, cy = (unsigned)fy, cz = (unsigned)fz;
    const float* tb = table + (unsigned)role * (TBLM + 1u) * 2u;
    const unsigned hy0 = cy * 2654435761u, hy1 = (cy + 1u) * 2654435761u;
    const unsigned hz0 = cz * 805459861u,  hz1 = (cz + 1u) * 805459861u;
#define LDC(dst, HX, HY, HZ) { const unsigned hh = ((HX) ^ (HY) ^ (HZ)) & TBLM; \
                               dst = *reinterpret_cast<const float2*>(tb + hh * 2u); }
    LDC(s.t0, cx,      hy0, hz0);
    LDC(s.t1, cx + 1u, hy0, hz0);
    LDC(s.t2, cx,      hy1, hz0);
    LDC(s.t3, cx + 1u, hy1, hz0);
    LDC(s.t4, cx,      hy0, hz1);
    LDC(s.t5, cx + 1u, hy0, hz1);
    LDC(s.t6, cx,      hy1, hz1);
    LDC(s.t7, cx + 1u, hy1, hz1);
#undef LDC
}

__device__ __forceinline__ void encode_finish(const GS& s, int role, _Float16* row)
{
    // trilinear-smoothstep interpolation of the 8 gathered entries
    const float ax = s.ax, ay = s.ay, az = s.az;
    const float bx = 1.f - ax, by = 1.f - ay, bz = 1.f - az;
    const float p00 = bx * by, p10 = ax * by, p01 = bx * ay, p11 = ax * ay;
    const float w0 = p00 * bz, w1 = p10 * bz, w2 = p01 * bz, w3 = p11 * bz;
    const float w4 = p00 * az, w5 = p10 * az, w6 = p01 * az, w7 = p11 * az;
    float g0 = w0 * s.t0.x, g1 = w0 * s.t0.y;
    g0 = fmaf(w1, s.t1.x, g0); g1 = fmaf(w1, s.t1.y, g1);
    g0 = fmaf(w2, s.t2.x, g0); g1 = fmaf(w2, s.t2.y, g1);
    g0 = fmaf(w3, s.t3.x, g0); g1 = fmaf(w3, s.t3.y, g1);
    g0 = fmaf(w4, s.t4.x, g0); g1 = fmaf(w4, s.t4.y, g1);
    g0 = fmaf(w5, s.t5.x, g0); g1 = fmaf(w5, s.t5.y, g1);
    g0 = fmaf(w6, s.t6.x, g0); g1 = fmaf(w6, s.t6.y, g1);
    g0 = fmaf(w7, s.t7.x, g0); g1 = fmaf(w7, s.t7.y, g1);
    half2v gh; gh[0] = (_Float16)g0; gh[1] = (_Float16)g1;
    *(half2v*)(row + 40 + 2 * role) = gh;      // grid feats, cols 40..47

    if (role == 0) {
        // xyz + fourier -> cols 0..39 (col 39 dead = 0)
        float e[40];
        e[0] = s.x0; e[1] = s.x1; e[2] = s.x2;
        const float a[3] = {s.x0, s.x1, s.x2};
        #pragma unroll
        for (int d = 0; d < 3; ++d)
            #pragma unroll
            for (int f = 0; f < 6; ++f) {
                const float ang = a[d] * (float)(1 << f);
                e[3 + d * 12 + f]     = __sinf(ang);
                e[3 + d * 12 + 6 + f] = __cosf(ang);
            }
        e[39] = 0.0f;
        #pragma unroll
        for (int chk = 0; chk < 5; ++chk) {
            half8 h;
            #pragma unroll
            for (int i = 0; i < 8; ++i) h[i] = (_Float16)e[chk * 8 + i];
            *(half8*)(row + chk * 8) = h;
        }
    } else if (role == 1) {
        // sh3 -> cols 64..79 (col 64 placeholder, L2 m4 overwrites with feat63)
        const float v0 = s.v0, v1 = s.v1, v2 = s.v2;
        float sh[9];
        sh[0] = 0.28209479177387814f;
        sh[1] = -0.4886025119029199f * v1;
        sh[2] =  0.4886025119029199f * v2;
        sh[3] = -0.4886025119029199f * v0;
        sh[4] =  1.0925484305920792f * v0 * v1;
        sh[5] = -1.0925484305920792f * v1 * v2;
        sh[6] =  0.9461746957575601f * v2 * v2 - 0.31539156525252005f;
        sh[7] = -1.0925484305920792f * v0 * v2;
        sh[8] =  0.5462742152960396f * (v0 * v0 - v1 * v1);
        half8 s0, s1;
        s0[0] = (_Float16)0.f;
        #pragma unroll
        for (int i = 0; i < 7; ++i) s0[i + 1] = (_Float16)sh[i];
        s1[0] = (_Float16)sh[7]; s1[1] = (_Float16)sh[8];
        #pragma unroll
        for (int i = 2; i < 8; ++i) s1[i] = (_Float16)0.f;
        *(half8*)(row + 64) = s0;
        *(half8*)(row + 72) = s1;
    }
    // roles 2,3: zero columns handled once before the chunk loop
}

__global__ __launch_bounds__(THR, 2)
void nerf_fwd(const float* __restrict__ x,
              const float* __restrict__ v,
              const float* __restrict__ table,
              const float* __restrict__ ws,
              float* __restrict__ out)
{
    // LDS: biases f32[224] @0 ; aB 64x104 f16 @896 ; bB 64x72 f16 @14208
    __shared__ __align__(16) unsigned char smem[23424];
    float*    sbias = (float*)smem;
    _Float16* aB    = (_Float16*)(smem + 896);
    _Float16* bB    = (_Float16*)(smem + 14208);

    const int tid  = threadIdx.x;
    const int lane = tid & 63;
    const int wv   = tid >> 6;       // 4 waves; wave owns points 16wv..16wv+15
    const int lr   = lane & 15;
    const int lg   = lane >> 4;
    const int role = lane & 3;
    const int ep   = (wv << 4) + (lane >> 2);   // encode point row (wave-private)
    const int gi0  = blockIdx.x * (CHUNK * CHUNKS);

    GS cur, nxt;
    // chunk-0 gathers go in flight; latency hides under weight/bias load
    gather_issue(gi0 + ep, role, x, v, table, cur);

    // ---- load ALL weight fragments into VGPRs (once per block) ----
    const _Float16* wsH = (const _Float16*)ws;
    half8 W1[4][2], W2[5][2], W3[4][3], W4[2];
    #pragma unroll
    for (int m = 0; m < 4; ++m)
        #pragma unroll
        for (int kc = 0; kc < 2; ++kc)
            W1[m][kc] = *(const half8*)(wsH + (m * 2 + kc) * 512 + lane * 8);
    #pragma unroll
    for (int m = 0; m < 5; ++m)
        #pragma unroll
        for (int kc = 0; kc < 2; ++kc)
            W2[m][kc] = *(const half8*)(wsH + 4096 + (m * 2 + kc) * 512 + lane * 8);
    #pragma unroll
    for (int m = 0; m < 4; ++m)
        #pragma unroll
        for (int kc = 0; kc < 3; ++kc)
            W3[m][kc] = *(const half8*)(wsH + 9216 + (m * 3 + kc) * 512 + lane * 8);
    #pragma unroll
    for (int kc = 0; kc < 2; ++kc)
        W4[kc] = *(const half8*)(wsH + 15360 + kc * 512 + lane * 8);

    // ---- stage biases (224 floats = 56 uint4) ----
    if (tid < 56) ((uint4*)sbias)[tid] = ((const uint4*)((const char*)ws + 32768))[tid];
    __syncthreads();   // the only barrier

    // ---- one-time zero-fill of constant-zero columns 48..95 (wave-private rows)
    {
        _Float16* rowp = aB + ep * 104;
        half8 z;
        #pragma unroll
        for (int i = 0; i < 8; ++i) z[i] = (_Float16)0.f;
        *(half8*)(rowp + 48 + 8 * role) = z;            // 48..79
        if (role < 2) *(half8*)(rowp + 80 + 8 * role) = z;  // 80..95
    }

    const int pt = (wv << 4) + lr;   // this wave's point rows in the MLP

    #pragma unroll 2
    for (int c = 0; c < CHUNKS; ++c) {
        const int cbase = gi0 + c * CHUNK;

        // finish encode for chunk c (consumes in-flight gathers)
        encode_finish(cur, role, aB + ep * 104);

        // issue chunk c+1 gathers BEFORE the MLP: latency hides under MFMA/DS
        if (c + 1 < CHUNKS)
            gather_issue(gi0 + (c + 1) * CHUNK + ep, role, x, v, table, nxt);

        // ================= L1: 64 -> 64, relu ==================================
        {
            const half8 B0 = *(const half8*)(aB + pt * 104 + 0 * 32 + lg * 8);
            const half8 B1 = *(const half8*)(aB + pt * 104 + 1 * 32 + lg * 8);
            #pragma unroll
            for (int m = 0; m < 4; ++m) {
                f32x4 cr = *(const f32x4*)(sbias + 0 + m * 16 + 4 * lg);
                cr = __builtin_amdgcn_mfma_f32_16x16x32_f16(W1[m][0], B0, cr, 0, 0, 0);
                cr = __builtin_amdgcn_mfma_f32_16x16x32_f16(W1[m][1], B1, cr, 0, 0, 0);
                half4v o4;
                #pragma unroll
                for (int r = 0; r < 4; ++r) o4[r] = (_Float16)fmaxf(cr[r], 0.f);
                *(half4v*)(bB + pt * 72 + 16 * m + 4 * lg) = o4;
            }
        }

        // ================= L2: 64 -> 65 (sigma row0, feat 1..64) ===============
        {
            const half8 B0 = *(const half8*)(bB + pt * 72 + 0 * 32 + lg * 8);
            const half8 B1 = *(const half8*)(bB + pt * 72 + 1 * 32 + lg * 8);
            #pragma unroll
            for (int m = 0; m < 4; ++m) {
                f32x4 cr = *(const f32x4*)(sbias + 64 + m * 16 + 4 * lg);
                cr = __builtin_amdgcn_mfma_f32_16x16x32_f16(W2[m][0], B0, cr, 0, 0, 0);
                cr = __builtin_amdgcn_mfma_f32_16x16x32_f16(W2[m][1], B1, cr, 0, 0, 0);
                half4v o4;
                #pragma unroll
                for (int r = 0; r < 4; ++r) o4[r] = (_Float16)fmaxf(cr[r], 0.f);
                *(half4v*)(aB + pt * 104 + 16 * m + 4 * lg) = o4;   // cols 0..63 (col0 dead)
                if (m == 0 && lg == 0)
                    out[cbase + pt] = __expf(cr[0]);                // sigma
            }
            {   // m=4: only row 64 (feat index 63) is real
                f32x4 cr = *(const f32x4*)(sbias + 64 + 4 * 16 + 4 * lg);
                cr = __builtin_amdgcn_mfma_f32_16x16x32_f16(W2[4][0], B0, cr, 0, 0, 0);
                cr = __builtin_amdgcn_mfma_f32_16x16x32_f16(W2[4][1], B1, cr, 0, 0, 0);
                if (lg == 0) aB[pt * 104 + 64] = (_Float16)fmaxf(cr[0], 0.f);
            }
        }

        // ================= L3: 96 -> 64, relu ==================================
        {
            const half8 B0 = *(const half8*)(aB + pt * 104 + 0 * 32 + lg * 8);
            const half8 B1 = *(const half8*)(aB + pt * 104 + 1 * 32 + lg * 8);
            const half8 B2 = *(const half8*)(aB + pt * 104 + 2 * 32 + lg * 8);
            #pragma unroll
            for (int m = 0; m < 4; ++m) {
                f32x4 cr = *(const f32x4*)(sbias + 144 + m * 16 + 4 * lg);
                cr = __builtin_amdgcn_mfma_f32_16x16x32_f16(W3[m][0], B0, cr, 0, 0, 0);
                cr = __builtin_amdgcn_mfma_f32_16x16x32_f16(W3[m][1], B1, cr, 0, 0, 0);
                cr = __builtin_amdgcn_mfma_f32_16x16x32_f16(W3[m][2], B2, cr, 0, 0, 0);
                half4v o4;
                #pragma unroll
                for (int r = 0; r < 4; ++r) o4[r] = (_Float16)fmaxf(cr[r], 0.f);
                *(half4v*)(bB + pt * 72 + 16 * m + 4 * lg) = o4;
            }
        }

        // ================= L4: 64 -> 3, sigmoid ================================
        {
            const half8 B0 = *(const half8*)(bB + pt * 72 + 0 * 32 + lg * 8);
            const half8 B1 = *(const half8*)(bB + pt * 72 + 1 * 32 + lg * 8);
            f32x4 cr = *(const f32x4*)(sbias + 208 + 4 * lg);
            cr = __builtin_amdgcn_mfma_f32_16x16x32_f16(W4[0], B0, cr, 0, 0, 0);
            cr = __builtin_amdgcn_mfma_f32_16x16x32_f16(W4[1], B1, cr, 0, 0, 0);
            if (lg == 0) {
                const int gpt = cbase + pt;
                #pragma unroll
                for (int r = 0; r < 3; ++r)
                    out[NPTS + 3 * gpt + r] = 1.0f / (1.0f + __expf(-cr[r]));
            }
        }

        if (c + 1 < CHUNKS) cur = nxt;
    }
}

extern "C" void kernel_launch(void* const* d_in, const int* in_sizes, int n_in,
                              void* d_out, int out_size, void* d_ws, size_t ws_size,
                              hipStream_t stream) {
    const float* x     = (const float*)d_in[0];
    const float* v     = (const float*)d_in[1];
    // d_in[2] = o, unused by the forward pass
    const float* table = (const float*)d_in[3];
    const float* dw1   = (const float*)d_in[4];
    const float* db1   = (const float*)d_in[5];
    const float* dw2   = (const float*)d_in[6];
    const float* db2   = (const float*)d_in[7];
    const float* rw1   = (const float*)d_in[8];
    const float* rb1   = (const float*)d_in[9];
    const float* rw2   = (const float*)d_in[10];
    const float* rb2   = (const float*)d_in[11];
    float* out = (float*)d_out;

    hipLaunchKernelGGL(prep, dim3(65), dim3(256), 0, stream,
                       dw1, db1, dw2, db2, rw1, rb1, rw2, rb2, d_ws);
    hipLaunchKernelGGL(nerf_fwd, dim3(GRID), dim3(THR), 0, stream,
                       x, v, table, (const float*)d_ws, out);
}

// Round 8
// 182.685 us; speedup vs baseline: 1.0671x; 1.0671x over previous
//
#include <hip/hip_runtime.h>

#define NPTS   524288
#define TBLM   ((1u << 19) - 1u)
#define THR    256
#define CHUNK  64
#define CHUNKS 4
#define GRID   (NPTS / (CHUNK * CHUNKS))   // 2048
#define TAB16_OFF   36864u
#define TAB16_BYTES (4u * 524288u * 2u * 2u)   // 8388608

typedef _Float16 half8  __attribute__((ext_vector_type(8)));
typedef _Float16 half4v __attribute__((ext_vector_type(4)));
typedef _Float16 half2v __attribute__((ext_vector_type(2)));
typedef float    f32x4  __attribute__((ext_vector_type(4)));

// d_ws: halves W1[m4][kc2][lane][j] @0 (4096) | W2[m5][kc2] @4096 | W3[m4][kc3] @9216
//       | W4[kc2] @15360 ; f32 biases @32768 (224) ; f16 table @36864 (8 MB, optional)
// W1 column permutation (k' = 32b + 8g + j, i = 8b+j):
//   i 0..5 -> sin(axis_g, 2^i) ; 6..11 -> cos(axis_g, 2^(i-6)) ; 12,13 -> grid level g
//   i 14 -> g0:x0, g3:x2 ; i 15 -> g0:x1 ; rest zero.  (axis_3 = dead, zero weights)

__global__ __launch_bounds__(256)
void prep(const float* __restrict__ dw1, const float* __restrict__ db1,
          const float* __restrict__ dw2, const float* __restrict__ db2,
          const float* __restrict__ rw1, const float* __restrict__ rb1,
          const float* __restrict__ rw2, const float* __restrict__ rb2,
          const float* __restrict__ table, void* __restrict__ ws, int doTab)
{
    const int b = blockIdx.x;
    if (b < 65) {
        const int t = b * 256 + threadIdx.x;
        if (t < 16384) {
            float w = 0.0f;
            if (t < 4096) {                       // W1 (new per-lane-computable permutation)
                const int u = t, mkc = u >> 9, m = mkc >> 1, kc = mkc & 1;
                const int lane = (u >> 3) & 63, j = u & 7;
                const int row = 16 * m + (lane & 15);
                const int kp  = kc * 32 + (lane >> 4) * 8 + j;
                const int g = (kp >> 3) & 3, i = ((kp >> 5) << 3) | (kp & 7);
                int ri = -1;
                if (i < 6)        ri = (g < 3) ? 3 + 12 * g + i : -1;
                else if (i < 12)  ri = (g < 3) ? 3 + 12 * g + 6 + (i - 6) : -1;
                else if (i == 12) ri = 39 + 2 * g;
                else if (i == 13) ri = 40 + 2 * g;
                else if (i == 14) ri = (g == 0) ? 0 : ((g == 3) ? 2 : -1);
                else              ri = (g == 0) ? 1 : -1;
                w = (ri >= 0) ? dw1[ri * 64 + row] : 0.0f;
            } else if (t < 9216) {                // W2 (unchanged, verified)
                const int u = t - 4096, mkc = u >> 9, m = mkc >> 1, kc = mkc & 1;
                const int lane = (u >> 3) & 63, j = u & 7;
                const int row = 16 * m + (lane & 15);
                const int k   = kc * 32 + (lane >> 4) * 8 + j;
                if (row < 65) w = dw2[k * 65 + row];
            } else if (t < 15360) {               // W3 (unchanged: col0 dead, feat@1..64, sh3@65..73)
                const int u = t - 9216, mkc = u >> 9, m = mkc / 3, kc = mkc - 3 * m;
                const int lane = (u >> 3) & 63, j = u & 7;
                const int row = 16 * m + (lane & 15);
                const int kp  = kc * 32 + (lane >> 4) * 8 + j;
                if (kp >= 1 && kp <= 73) w = rw1[(kp - 1) * 64 + row];
            } else {                              // W4 (unchanged)
                const int u = t - 15360, kc = u >> 9;
                const int lane = (u >> 3) & 63, j = u & 7;
                const int row = lane & 15;
                const int k   = kc * 32 + (lane >> 4) * 8 + j;
                if (row < 3) w = rw2[k * 3 + row];
            }
            ((_Float16*)ws)[t] = (_Float16)w;
        } else if (t < 16384 + 224) {
            const int u = t - 16384;
            float bv = 0.0f;
            if (u < 64)        bv = db1[u];
            else if (u < 144)  { const int r = u - 64;  if (r < 65) bv = db2[r]; }
            else if (u < 208)  bv = rb1[u - 144];
            else               { const int r = u - 208; if (r < 3)  bv = rb2[r]; }
            ((float*)((char*)ws + 32768))[u] = bv;
        }
    } else if (doTab) {
        // convert hash table (levels 0..3) to f16, same [lv][entry][feat] layout
        const int t2 = (b - 65) * 256 + (int)threadIdx.x;        // 0..524287
        const float4* src = (const float4*)(table + (size_t)t2 * 8);
        const float4 f0 = src[0], f1 = src[1];
        half8 h;
        h[0] = (_Float16)f0.x; h[1] = (_Float16)f0.y; h[2] = (_Float16)f0.z; h[3] = (_Float16)f0.w;
        h[4] = (_Float16)f1.x; h[5] = (_Float16)f1.y; h[6] = (_Float16)f1.z; h[7] = (_Float16)f1.w;
        *(half8*)((_Float16*)((char*)ws + TAB16_OFF) + (size_t)t2 * 8) = h;
    }
}

__device__ __forceinline__ float sstep(float t) { return t * t * (3.0f - 2.0f * t); }

struct GS {
    float x0, x1, x2, v0, v1, v2;
    float ax, ay, az;
    float2 f0, f1, f2, f3, f4, f5, f6, f7;      // f32-table path
    unsigned h0, h1, h2, h3, h4, h5, h6, h7;    // f16-table path (half2 in u32)
};

template<bool F16T>
__device__ __forceinline__ void gather_issue(int gi, int lg,
    const float* __restrict__ x, const float* __restrict__ v,
    const float* __restrict__ tab32, const _Float16* __restrict__ tab16, GS& s)
{
    s.x0 = x[3 * gi + 0]; s.x1 = x[3 * gi + 1]; s.x2 = x[3 * gi + 2];
    s.v0 = v[3 * gi + 0]; s.v1 = v[3 * gi + 1]; s.v2 = v[3 * gi + 2];
    const float rf = (lg == 0) ? 33.f : (lg == 1) ? 43.f : (lg == 2) ? 56.f : 74.f;
    const float px = (s.x0 + 1.f) * 0.5f * rf;
    const float py = (s.x1 + 1.f) * 0.5f * rf;
    const float pz = (s.x2 + 1.f) * 0.5f * rf;
    const float fx = floorf(px), fy = floorf(py), fz = floorf(pz);
    s.ax = sstep(px - fx); s.ay = sstep(py - fy); s.az = sstep(pz - fz);
    const unsigned cx = (unsigned)fx, cy = (unsigned)fy, cz = (unsigned)fz;
    const unsigned hy0 = cy * 2654435761u, hy1 = (cy + 1u) * 2654435761u;
    const unsigned hz0 = cz * 805459861u,  hz1 = (cz + 1u) * 805459861u;
    if (F16T) {
        const _Float16* tb = tab16 + (unsigned)lg * ((TBLM + 1u) * 2u);
#define LDH(dst, HX, HY, HZ) { const unsigned hh = ((HX) ^ (HY) ^ (HZ)) & TBLM; \
                               dst = *reinterpret_cast<const unsigned*>(tb + hh * 2u); }
        LDH(s.h0, cx,      hy0, hz0); LDH(s.h1, cx + 1u, hy0, hz0);
        LDH(s.h2, cx,      hy1, hz0); LDH(s.h3, cx + 1u, hy1, hz0);
        LDH(s.h4, cx,      hy0, hz1); LDH(s.h5, cx + 1u, hy0, hz1);
        LDH(s.h6, cx,      hy1, hz1); LDH(s.h7, cx + 1u, hy1, hz1);
#undef LDH
    } else {
        const float* tb = tab32 + (unsigned)lg * ((TBLM + 1u) * 2u);
#define LDF(dst, HX, HY, HZ) { const unsigned hh = ((HX) ^ (HY) ^ (HZ)) & TBLM; \
                               dst = *reinterpret_cast<const float2*>(tb + hh * 2u); }
        LDF(s.f0, cx,      hy0, hz0); LDF(s.f1, cx + 1u, hy0, hz0);
        LDF(s.f2, cx,      hy1, hz0); LDF(s.f3, cx + 1u, hy1, hz0);
        LDF(s.f4, cx,      hy0, hz1); LDF(s.f5, cx + 1u, hy0, hz1);
        LDF(s.f6, cx,      hy1, hz1); LDF(s.f7, cx + 1u, hy1, hz1);
#undef LDF
    }
}

template<bool F16T>
__device__ __forceinline__ void build_B01(const GS& s, int lg, half8& B0, half8& B1)
{
    // trilinear-smoothstep interp of this lane's level
    const float ax = s.ax, ay = s.ay, az = s.az;
    const float bx = 1.f - ax, by = 1.f - ay, bz = 1.f - az;
    const float p00 = bx * by, p10 = ax * by, p01 = bx * ay, p11 = ax * ay;
    const float w0 = p00 * bz, w1 = p10 * bz, w2 = p01 * bz, w3 = p11 * bz;
    const float w4 = p00 * az, w5 = p10 * az, w6 = p01 * az, w7 = p11 * az;
    float e0[8], e1[8];
    if (F16T) {
        const unsigned hv[8] = {s.h0, s.h1, s.h2, s.h3, s.h4, s.h5, s.h6, s.h7};
        #pragma unroll
        for (int i = 0; i < 8; ++i) {
            const half2v h = __builtin_bit_cast(half2v, hv[i]);
            e0[i] = (float)h[0]; e1[i] = (float)h[1];
        }
    } else {
        const float2 fv[8] = {s.f0, s.f1, s.f2, s.f3, s.f4, s.f5, s.f6, s.f7};
        #pragma unroll
        for (int i = 0; i < 8; ++i) { e0[i] = fv[i].x; e1[i] = fv[i].y; }
    }
    const float wts[8] = {w0, w1, w2, w3, w4, w5, w6, w7};
    float glo = 0.f, ghi = 0.f;
    #pragma unroll
    for (int i = 0; i < 8; ++i) { glo = fmaf(wts[i], e0[i], glo); ghi = fmaf(wts[i], e1[i], ghi); }

    // fourier axis for this lane group via double-angle (2 transcendentals)
    const float a = (lg == 0) ? s.x0 : (lg == 1) ? s.x1 : s.x2;   // lg3: dead (zero W cols)
    float sv[6], cv[6];
    sv[0] = __sinf(a); cv[0] = __cosf(a);
    #pragma unroll
    for (int f = 1; f < 6; ++f) {
        const float ss = sv[f - 1], cc = cv[f - 1];
        sv[f] = 2.f * ss * cc;
        cv[f] = fmaf(-2.f * ss, ss, 1.f);
    }
    const float ex0 = (lg == 0) ? s.x0 : s.x2;   // weights select g0/g3
    const float ex1 = s.x1;                      // weight nonzero only for g0
    B0[0] = (_Float16)sv[0]; B0[1] = (_Float16)sv[1]; B0[2] = (_Float16)sv[2];
    B0[3] = (_Float16)sv[3]; B0[4] = (_Float16)sv[4]; B0[5] = (_Float16)sv[5];
    B0[6] = (_Float16)cv[0]; B0[7] = (_Float16)cv[1];
    B1[0] = (_Float16)cv[2]; B1[1] = (_Float16)cv[3]; B1[2] = (_Float16)cv[4];
    B1[3] = (_Float16)cv[5]; B1[4] = (_Float16)glo;   B1[5] = (_Float16)ghi;
    B1[6] = (_Float16)ex0;   B1[7] = (_Float16)ex1;
}

template<bool F16T>
__global__ __launch_bounds__(THR, 2)
void nerf_fwd(const float* __restrict__ x,
              const float* __restrict__ v,
              const float* __restrict__ table,
              const float* __restrict__ ws,
              float* __restrict__ out)
{
    // LDS: biases f32[224] @0 ; bB 64x72 f16 @896   (10112 B total)
    __shared__ __align__(16) unsigned char smem[10112];
    float*    sbias = (float*)smem;
    _Float16* bB    = (_Float16*)(smem + 896);

    const int tid  = threadIdx.x;
    const int lane = tid & 63;
    const int wv   = tid >> 6;
    const int lr   = lane & 15;
    const int lg   = lane >> 4;
    const int pt   = (wv << 4) + lr;
    const int gi0  = blockIdx.x * (CHUNK * CHUNKS);
    const _Float16* tab16 = (const _Float16*)((const char*)ws + TAB16_OFF);

    GS cur, nxt;
    gather_issue<F16T>(gi0 + pt, lg, x, v, table, tab16, cur);

    // ---- all weight fragments -> VGPRs (once per block) ----
    const _Float16* wsH = (const _Float16*)ws;
    half8 W1[4][2], W2[5][2], W3[4][3], W4[2];
    #pragma unroll
    for (int m = 0; m < 4; ++m)
        #pragma unroll
        for (int kc = 0; kc < 2; ++kc)
            W1[m][kc] = *(const half8*)(wsH + (m * 2 + kc) * 512 + lane * 8);
    #pragma unroll
    for (int m = 0; m < 5; ++m)
        #pragma unroll
        for (int kc = 0; kc < 2; ++kc)
            W2[m][kc] = *(const half8*)(wsH + 4096 + (m * 2 + kc) * 512 + lane * 8);
    #pragma unroll
    for (int m = 0; m < 4; ++m)
        #pragma unroll
        for (int kc = 0; kc < 3; ++kc)
            W3[m][kc] = *(const half8*)(wsH + 9216 + (m * 3 + kc) * 512 + lane * 8);
    #pragma unroll
    for (int kc = 0; kc < 2; ++kc)
        W4[kc] = *(const half8*)(wsH + 15360 + kc * 512 + lane * 8);

    if (tid < 56) ((uint4*)sbias)[tid] = ((const uint4*)((const char*)ws + 32768))[tid];
    __syncthreads();   // the only barrier

    #pragma unroll 2
    for (int c = 0; c < CHUNKS; ++c) {
        const int cbase = gi0 + c * CHUNK;

        // L1 inputs built fully in registers (no LDS, no divergence)
        half8 B0, B1;
        build_B01<F16T>(cur, lg, B0, B1);

        if (c + 1 < CHUNKS)
            gather_issue<F16T>(gi0 + (c + 1) * CHUNK + pt, lg, x, v, table, tab16, nxt);

        // ================= L1: 64 -> 64, relu =================================
        #pragma unroll
        for (int m = 0; m < 4; ++m) {
            f32x4 cr = *(const f32x4*)(sbias + 0 + m * 16 + 4 * lg);
            cr = __builtin_amdgcn_mfma_f32_16x16x32_f16(W1[m][0], B0, cr, 0, 0, 0);
            cr = __builtin_amdgcn_mfma_f32_16x16x32_f16(W1[m][1], B1, cr, 0, 0, 0);
            half4v o4;
            #pragma unroll
            for (int r = 0; r < 4; ++r) o4[r] = (_Float16)fmaxf(cr[r], 0.f);
            *(half4v*)(bB + pt * 72 + 16 * m + 4 * lg) = o4;
        }

        // ================= L2: 64 -> 65 (sigma row0, feats) ===================
        float f63;
        {
            const half8 C0 = *(const half8*)(bB + pt * 72 + 0 * 32 + lg * 8);
            const half8 C1 = *(const half8*)(bB + pt * 72 + 1 * 32 + lg * 8);
            #pragma unroll
            for (int m = 0; m < 4; ++m) {
                f32x4 cr = *(const f32x4*)(sbias + 64 + m * 16 + 4 * lg);
                cr = __builtin_amdgcn_mfma_f32_16x16x32_f16(W2[m][0], C0, cr, 0, 0, 0);
                cr = __builtin_amdgcn_mfma_f32_16x16x32_f16(W2[m][1], C1, cr, 0, 0, 0);
                half4v o4;
                #pragma unroll
                for (int r = 0; r < 4; ++r) o4[r] = (_Float16)fmaxf(cr[r], 0.f);
                *(half4v*)(bB + pt * 72 + 16 * m + 4 * lg) = o4;  // cols 0..63 (col0 dead)
                if (m == 0 && lg == 0)
                    out[cbase + pt] = __expf(cr[0]);              // sigma
            }
            f32x4 cr = *(const f32x4*)(sbias + 64 + 4 * 16 + 4 * lg);
            cr = __builtin_amdgcn_mfma_f32_16x16x32_f16(W2[4][0], C0, cr, 0, 0, 0);
            cr = __builtin_amdgcn_mfma_f32_16x16x32_f16(W2[4][1], C1, cr, 0, 0, 0);
            f63 = fmaxf(cr[0], 0.f);                              // row64 at lg0 only
        }

        // ================= L3: 96 -> 64, relu (B2 in registers) ===============
        {
            // sh3 (all lanes) + per-lg packing: lg0=[f63,sh0..6], lg1=[sh7,sh8,0..], lg2/3=0
            const float v0 = cur.v0, v1 = cur.v1, v2 = cur.v2;
            const float sh0 = 0.28209479177387814f;
            const float sh1 = -0.4886025119029199f * v1;
            const float sh2 =  0.4886025119029199f * v2;
            const float sh3v = -0.4886025119029199f * v0;
            const float sh4 =  1.0925484305920792f * v0 * v1;
            const float sh5 = -1.0925484305920792f * v1 * v2;
            const float sh6 =  0.9461746957575601f * v2 * v2 - 0.31539156525252005f;
            const float sh7 = -1.0925484305920792f * v0 * v2;
            const float sh8 =  0.5462742152960396f * (v0 * v0 - v1 * v1);
            const bool g0 = (lg == 0), g1 = (lg == 1);
            half8 B2;
            B2[0] = (_Float16)(g0 ? f63 : (g1 ? sh7 : 0.f));
            B2[1] = (_Float16)(g0 ? sh0 : (g1 ? sh8 : 0.f));
            B2[2] = (_Float16)(g0 ? sh1 : 0.f);
            B2[3] = (_Float16)(g0 ? sh2 : 0.f);
            B2[4] = (_Float16)(g0 ? sh3v : 0.f);
            B2[5] = (_Float16)(g0 ? sh4 : 0.f);
            B2[6] = (_Float16)(g0 ? sh5 : 0.f);
            B2[7] = (_Float16)(g0 ? sh6 : 0.f);

            const half8 C0 = *(const half8*)(bB + pt * 72 + 0 * 32 + lg * 8);
            const half8 C1 = *(const half8*)(bB + pt * 72 + 1 * 32 + lg * 8);
            #pragma unroll
            for (int m = 0; m < 4; ++m) {
                f32x4 cr = *(const f32x4*)(sbias + 144 + m * 16 + 4 * lg);
                cr = __builtin_amdgcn_mfma_f32_16x16x32_f16(W3[m][0], C0, cr, 0, 0, 0);
                cr = __builtin_amdgcn_mfma_f32_16x16x32_f16(W3[m][1], C1, cr, 0, 0, 0);
                cr = __builtin_amdgcn_mfma_f32_16x16x32_f16(W3[m][2], B2, cr, 0, 0, 0);
                half4v o4;
                #pragma unroll
                for (int r = 0; r < 4; ++r) o4[r] = (_Float16)fmaxf(cr[r], 0.f);
                *(half4v*)(bB + pt * 72 + 16 * m + 4 * lg) = o4;
            }
        }

        // ================= L4: 64 -> 3, sigmoid ===============================
        {
            const half8 C0 = *(const half8*)(bB + pt * 72 + 0 * 32 + lg * 8);
            const half8 C1 = *(const half8*)(bB + pt * 72 + 1 * 32 + lg * 8);
            f32x4 cr = *(const f32x4*)(sbias + 208 + 4 * lg);
            cr = __builtin_amdgcn_mfma_f32_16x16x32_f16(W4[0], C0, cr, 0, 0, 0);
            cr = __builtin_amdgcn_mfma_f32_16x16x32_f16(W4[1], C1, cr, 0, 0, 0);
            if (lg == 0) {
                const int gpt = cbase + pt;
                #pragma unroll
                for (int r = 0; r < 3; ++r)
                    out[NPTS + 3 * gpt + r] = 1.0f / (1.0f + __expf(-cr[r]));
            }
        }

        if (c + 1 < CHUNKS) cur = nxt;
    }
}

extern "C" void kernel_launch(void* const* d_in, const int* in_sizes, int n_in,
                              void* d_out, int out_size, void* d_ws, size_t ws_size,
                              hipStream_t stream) {
    const float* x     = (const float*)d_in[0];
    const float* v     = (const float*)d_in[1];
    // d_in[2] = o, unused by the forward pass
    const float* table = (const float*)d_in[3];
    const float* dw1   = (const float*)d_in[4];
    const float* db1   = (const float*)d_in[5];
    const float* dw2   = (const float*)d_in[6];
    const float* db2   = (const float*)d_in[7];
    const float* rw1   = (const float*)d_in[8];
    const float* rb1   = (const float*)d_in[9];
    const float* rw2   = (const float*)d_in[10];
    const float* rb2   = (const float*)d_in[11];
    float* out = (float*)d_out;

    const bool useF16 = (ws_size >= (size_t)TAB16_OFF + TAB16_BYTES);
    const int prepBlocks = useF16 ? (65 + 2048) : 65;
    hipLaunchKernelGGL(prep, dim3(prepBlocks), dim3(256), 0, stream,
                       dw1, db1, dw2, db2, rw1, rb1, rw2, rb2, table, d_ws,
                       useF16 ? 1 : 0);
    if (useF16)
        hipLaunchKernelGGL((nerf_fwd<true>), dim3(GRID), dim3(THR), 0, stream,
                           x, v, table, (const float*)d_ws, out);
    else
        hipLaunchKernelGGL((nerf_fwd<false>), dim3(GRID), dim3(THR), 0, stream,
                           x, v, table, (const float*)d_ws, out);
}